// Round 8
// baseline (162.671 us; speedup 1.0000x reference)
//
#include <hip/hip_runtime.h>
#include <math.h>

// ListNet segment-softmax CE, sorted week indices.
// BATCH = 4194304, NUM_WEEKS = 262144, avg 16 items/week.
//
// Per-week loss = T/S_l - log(S_s);  S_l = sum e^l, S_s = sum e^s, T = sum e^l*s.
// (eps inside log dropped; validated rounds 2-7, absmax 0.0)
//
// Round-8: K=4 ownership -> lane-contiguous 16B loads = fully coalesced in
// TA (4 lanes/cacheline), NO staging, NO scan. r3's coalesced attempt lost
// to per-block overheads (1024-item blocks, full-SLOTS init), not to the
// LDS flush: here blocks own 4096 items (r5-proven), init covers only
// span+1 slots, and the finalize is FUSED via the last-block-done idiom
// (threadfence + device atomic counter), killing the 2nd launch.

#define TPB 256
#define K 4
#define CHUNK (TPB * K)   // 4096 items per block
#define SLOTS 768         // > max span+1 (~256 expected)

__global__ __launch_bounds__(TPB) void fused(
        const float* __restrict__ scores, const float* __restrict__ labels,
        const int* __restrict__ widx,
        int* __restrict__ rec_week, float* __restrict__ rec_el,
        float* __restrict__ rec_es, float* __restrict__ rec_tl,
        int* __restrict__ rec_cnt,
        float* __restrict__ part_loss, int* __restrict__ part_nv,
        unsigned int* __restrict__ done, int nb, float* __restrict__ out) {
    __shared__ float lel[SLOTS], les[SLOTS], ltl[SLOTS];
    __shared__ int   lcnt[SLOTS];
    __shared__ float ra4[4];
    __shared__ int   rn4[4];
    __shared__ float rb4[4];
    __shared__ int   rm4[4];
    __shared__ int   is_last;

    const int tid = threadIdx.x;
    const int lane = tid & 63, wv = tid >> 6;
    const int base = blockIdx.x * CHUNK;

    // coalesced per-thread quad (lane-contiguous 16B)
    const int i0 = base + tid * K;
    const int4   w4 = *reinterpret_cast<const int4*>(widx + i0);
    const float4 l4 = *reinterpret_cast<const float4*>(labels + i0);
    const float4 s4 = *reinterpret_cast<const float4*>(scores + i0);
    const int w0 = widx[base];                // same-address: TA broadcast
    const int wl = widx[base + CHUNK - 1];
    const int span = wl - w0;

    for (int s = tid; s <= span; s += TPB) {  // init only live slots
        lel[s] = 0.f; les[s] = 0.f; ltl[s] = 0.f; lcnt[s] = 0;
    }
    __syncthreads();

    const float el0 = __expf(l4.x), el1 = __expf(l4.y), el2 = __expf(l4.z), el3 = __expf(l4.w);
    const float es0 = __expf(s4.x), es1 = __expf(s4.y), es2 = __expf(s4.z), es3 = __expf(s4.w);

    // sequential run merge over the 4 items; flush each run (r3 pattern)
    int cw = w4.x; float ra = el0, rb = es0, rt = el0 * s4.x; int rc = 1;
#define FLUSH()                                                                \
    {                                                                          \
        const int s = cw - w0;                                                 \
        atomicAdd(&lel[s], ra); atomicAdd(&les[s], rb);                        \
        atomicAdd(&ltl[s], rt); atomicAdd(&lcnt[s], rc);                       \
    }
#define ITEM(wv_, el_, es_, sv_)                                               \
    {                                                                          \
        if ((wv_) == cw) { ra += (el_); rb += (es_); rt += (el_) * (sv_); ++rc; } \
        else { FLUSH(); cw = (wv_); ra = (el_); rb = (es_); rt = (el_) * (sv_); rc = 1; } \
    }
    ITEM(w4.y, el1, es1, s4.y)
    ITEM(w4.z, el2, es2, s4.z)
    ITEM(w4.w, el3, es3, s4.w)
    FLUSH();
#undef ITEM
#undef FLUSH
    __syncthreads();

    // interior slots (strictly between w0 and wl) complete in this block
    float loss = 0.f; int nv = 0;
    for (int s = 1 + tid; s < span; s += TPB) {
        const int c = lcnt[s];
        if (c >= 2) { loss += ltl[s] / lel[s] - __logf(les[s]); ++nv; }
    }
    #pragma unroll
    for (int off = 32; off; off >>= 1) {
        loss += __shfl_down(loss, off);
        nv   += __shfl_down(nv, off);
    }
    if (lane == 0) { ra4[wv] = loss; rn4[wv] = nv; }
    __syncthreads();
    if (tid == 0) {
        part_loss[blockIdx.x] = ra4[0] + ra4[1] + ra4[2] + ra4[3];
        part_nv[blockIdx.x]   = rn4[0] + rn4[1] + rn4[2] + rn4[3];
        const int b2 = blockIdx.x * 2;
        rec_week[b2] = w0;
        rec_el[b2] = lel[0]; rec_es[b2] = les[0];
        rec_tl[b2] = ltl[0]; rec_cnt[b2] = lcnt[0];
        rec_week[b2 + 1] = wl;
        if (span > 0) {
            rec_el[b2 + 1] = lel[span]; rec_es[b2 + 1] = les[span];
            rec_tl[b2 + 1] = ltl[span]; rec_cnt[b2 + 1] = lcnt[span];
        } else {  // single-week block: zero filler keeps run-adjacency intact
            rec_el[b2 + 1] = 0.f; rec_es[b2 + 1] = 0.f;
            rec_tl[b2 + 1] = 0.f; rec_cnt[b2 + 1] = 0;
        }
        __threadfence();                       // records visible device-wide
        const unsigned int old = atomicAdd(done, 1u);
        is_last = (old == (unsigned int)(nb - 1));
    }
    __syncthreads();
    if (!is_last) return;

    // ---- last block: merge boundary records + partials, write scalar ----
    __threadfence();                           // acquire all blocks' writes
    const int nrec = nb * 2;
    float L = 0.f; int NV = 0;
    for (int j = tid; j < nrec; j += TPB) {
        const int w = rec_week[j];
        if (j > 0 && rec_week[j - 1] == w) continue;  // not a run head
        float a = rec_el[j], b = rec_es[j], t = rec_tl[j];
        int c = rec_cnt[j];
        for (int k = j + 1; k < nrec && rec_week[k] == w; ++k) {
            a += rec_el[k]; b += rec_es[k]; t += rec_tl[k]; c += rec_cnt[k];
        }
        if (c >= 2) { L += t / a - __logf(b); ++NV; }
    }
    for (int j = tid; j < nb; j += TPB) { L += part_loss[j]; NV += part_nv[j]; }
    #pragma unroll
    for (int off = 32; off; off >>= 1) {
        L  += __shfl_down(L, off);
        NV += __shfl_down(NV, off);
    }
    if (lane == 0) { rb4[wv] = L; rm4[wv] = NV; }
    __syncthreads();
    if (tid == 0) {
        const float tl = rb4[0] + rb4[1] + rb4[2] + rb4[3];
        const int   tn = rm4[0] + rm4[1] + rm4[2] + rm4[3];
        out[0] = (tn > 0) ? (-tl / (float)tn) : 0.f;
    }
}

extern "C" void kernel_launch(void* const* d_in, const int* in_sizes, int n_in,
                              void* d_out, int out_size, void* d_ws, size_t ws_size,
                              hipStream_t stream) {
    const float* scores = (const float*)d_in[0];
    const float* labels = (const float*)d_in[1];
    const int*   widx   = (const int*)d_in[2];
    const int n  = in_sizes[0];
    const int nb = n / CHUNK;      // 1024
    const int nrec = nb * 2;

    char* ws = (char*)d_ws;
    size_t off = 0;
    int*   rec_week = (int*)  (ws + off); off += (size_t)nrec * 4;
    float* rec_el   = (float*)(ws + off); off += (size_t)nrec * 4;
    float* rec_es   = (float*)(ws + off); off += (size_t)nrec * 4;
    float* rec_tl   = (float*)(ws + off); off += (size_t)nrec * 4;
    int*   rec_cnt  = (int*)  (ws + off); off += (size_t)nrec * 4;
    float* part_loss= (float*)(ws + off); off += (size_t)nb * 4;
    int*   part_nv  = (int*)  (ws + off); off += (size_t)nb * 4;
    unsigned int* done = (unsigned int*)(ws + off);

    float* out = (float*)d_out;

    hipMemsetAsync(done, 0, 4, stream);        // graph-capturable
    fused<<<nb, TPB, 0, stream>>>(scores, labels, widx,
                                  rec_week, rec_el, rec_es, rec_tl, rec_cnt,
                                  part_loss, part_nv, done, nb, out);
}

// Round 9
// 47.765 us; speedup vs baseline: 3.4056x; 3.4056x over previous
//
#include <hip/hip_runtime.h>
#include <math.h>

// ListNet segment-softmax CE, sorted week indices.
// BATCH = 4194304, NUM_WEEKS = 262144, avg 16 items/week.
//
// Per-week loss = T/S_l - log(S_s);  S_l = sum e^l, S_s = sum e^s, T = sum e^l*s.
// (eps inside log dropped; validated rounds 2-8, absmax 0.0)
//
// Round-9 = round-8 WITHOUT the fused finalize. r8 post-mortem: the
// last-block-done idiom cost ~140us — 1024 per-block __threadfence()s are
// device-scope releases, i.e. per-XCD L2 writebacks on this 8-XCD chip
// (G16: L2s not cross-coherent). Two kernels it is.
//   main_pass: K=4 per thread -> lane-contiguous 16B loads (fully coalesced,
//     4 lanes/cacheline), NO staging, NO scan. Runs merged serially within
//     the quad; every run flushed to LDS slot (w - w0) via ds atomics.
//     Interior slots finalized block-locally; 2 boundary records/block.
//   finalize: 1 block, merges 2048 records + 1024 partials.

#define TPB 256
#define K 4
#define CHUNK (TPB * K)   // 4096 items per block
#define SLOTS 768         // > max span+1 (~256 expected)

__global__ __launch_bounds__(TPB) void main_pass(
        const float* __restrict__ scores, const float* __restrict__ labels,
        const int* __restrict__ widx,
        int* __restrict__ rec_week, float* __restrict__ rec_el,
        float* __restrict__ rec_es, float* __restrict__ rec_tl,
        int* __restrict__ rec_cnt,
        float* __restrict__ part_loss, int* __restrict__ part_nv) {
    __shared__ float lel[SLOTS], les[SLOTS], ltl[SLOTS];
    __shared__ int   lcnt[SLOTS];
    __shared__ float ra4[4];
    __shared__ int   rn4[4];

    const int tid = threadIdx.x;
    const int lane = tid & 63, wv = tid >> 6;
    const int base = blockIdx.x * CHUNK;

    // coalesced per-thread quad (lane-contiguous 16B)
    const int i0 = base + tid * K;
    const int4   w4 = *reinterpret_cast<const int4*>(widx + i0);
    const float4 l4 = *reinterpret_cast<const float4*>(labels + i0);
    const float4 s4 = *reinterpret_cast<const float4*>(scores + i0);
    const int w0 = widx[base];                // same-address: broadcast
    const int wl = widx[base + CHUNK - 1];
    const int span = wl - w0;

    for (int s = tid; s <= span; s += TPB) {  // init only live slots
        lel[s] = 0.f; les[s] = 0.f; ltl[s] = 0.f; lcnt[s] = 0;
    }
    __syncthreads();

    const float el0 = __expf(l4.x), el1 = __expf(l4.y), el2 = __expf(l4.z), el3 = __expf(l4.w);
    const float es0 = __expf(s4.x), es1 = __expf(s4.y), es2 = __expf(s4.z), es3 = __expf(s4.w);

    // sequential run merge over the 4 items; flush each run
    int cw = w4.x; float ra = el0, rb = es0, rt = el0 * s4.x; int rc = 1;
#define FLUSH()                                                                \
    {                                                                          \
        const int s = cw - w0;                                                 \
        atomicAdd(&lel[s], ra); atomicAdd(&les[s], rb);                        \
        atomicAdd(&ltl[s], rt); atomicAdd(&lcnt[s], rc);                       \
    }
#define ITEM(wv_, el_, es_, sv_)                                               \
    {                                                                          \
        if ((wv_) == cw) { ra += (el_); rb += (es_); rt += (el_) * (sv_); ++rc; } \
        else { FLUSH(); cw = (wv_); ra = (el_); rb = (es_); rt = (el_) * (sv_); rc = 1; } \
    }
    ITEM(w4.y, el1, es1, s4.y)
    ITEM(w4.z, el2, es2, s4.z)
    ITEM(w4.w, el3, es3, s4.w)
    FLUSH();
#undef ITEM
#undef FLUSH
    __syncthreads();

    // interior slots (strictly between w0 and wl) complete in this block
    float loss = 0.f; int nv = 0;
    for (int s = 1 + tid; s < span; s += TPB) {
        const int c = lcnt[s];
        if (c >= 2) { loss += ltl[s] / lel[s] - __logf(les[s]); ++nv; }
    }
    #pragma unroll
    for (int off = 32; off; off >>= 1) {
        loss += __shfl_down(loss, off);
        nv   += __shfl_down(nv, off);
    }
    if (lane == 0) { ra4[wv] = loss; rn4[wv] = nv; }
    __syncthreads();
    if (tid == 0) {
        part_loss[blockIdx.x] = ra4[0] + ra4[1] + ra4[2] + ra4[3];
        part_nv[blockIdx.x]   = rn4[0] + rn4[1] + rn4[2] + rn4[3];
        const int b2 = blockIdx.x * 2;
        rec_week[b2] = w0;
        rec_el[b2] = lel[0]; rec_es[b2] = les[0];
        rec_tl[b2] = ltl[0]; rec_cnt[b2] = lcnt[0];
        rec_week[b2 + 1] = wl;
        if (span > 0) {
            rec_el[b2 + 1] = lel[span]; rec_es[b2 + 1] = les[span];
            rec_tl[b2 + 1] = ltl[span]; rec_cnt[b2 + 1] = lcnt[span];
        } else {  // single-week block: zero filler keeps run-adjacency intact
            rec_el[b2 + 1] = 0.f; rec_es[b2 + 1] = 0.f;
            rec_tl[b2 + 1] = 0.f; rec_cnt[b2 + 1] = 0;
        }
    }
}

__global__ __launch_bounds__(1024) void finalize(
        const int* __restrict__ rec_week, const float* __restrict__ rec_el,
        const float* __restrict__ rec_es, const float* __restrict__ rec_tl,
        const int* __restrict__ rec_cnt,
        const float* __restrict__ part_loss, const int* __restrict__ part_nv,
        int nrec, int nb, float* __restrict__ out) {
    const int tid = threadIdx.x;
    float loss = 0.f; int nv = 0;
    for (int j = tid; j < nrec; j += 1024) {
        const int w = rec_week[j];
        if (j > 0 && rec_week[j - 1] == w) continue;  // not a run head
        float a = rec_el[j], b = rec_es[j], t = rec_tl[j];
        int c = rec_cnt[j];
        for (int k = j + 1; k < nrec && rec_week[k] == w; ++k) {
            a += rec_el[k]; b += rec_es[k]; t += rec_tl[k]; c += rec_cnt[k];
        }
        if (c >= 2) { loss += t / a - __logf(b); ++nv; }
    }
    for (int j = tid; j < nb; j += 1024) { loss += part_loss[j]; nv += part_nv[j]; }
    #pragma unroll
    for (int off = 32; off; off >>= 1) {
        loss += __shfl_down(loss, off);
        nv   += __shfl_down(nv, off);
    }
    __shared__ float ra[16];
    __shared__ int   rn[16];
    const int lane = tid & 63, wv = tid >> 6;
    if (lane == 0) { ra[wv] = loss; rn[wv] = nv; }
    __syncthreads();
    if (tid == 0) {
        float tl = 0.f; int tn = 0;
        for (int k = 0; k < 16; ++k) { tl += ra[k]; tn += rn[k]; }
        out[0] = (tn > 0) ? (-tl / (float)tn) : 0.f;
    }
}

extern "C" void kernel_launch(void* const* d_in, const int* in_sizes, int n_in,
                              void* d_out, int out_size, void* d_ws, size_t ws_size,
                              hipStream_t stream) {
    const float* scores = (const float*)d_in[0];
    const float* labels = (const float*)d_in[1];
    const int*   widx   = (const int*)d_in[2];
    const int n  = in_sizes[0];
    const int nb = n / CHUNK;      // 1024
    const int nrec = nb * 2;

    char* ws = (char*)d_ws;
    size_t off = 0;
    int*   rec_week = (int*)  (ws + off); off += (size_t)nrec * 4;
    float* rec_el   = (float*)(ws + off); off += (size_t)nrec * 4;
    float* rec_es   = (float*)(ws + off); off += (size_t)nrec * 4;
    float* rec_tl   = (float*)(ws + off); off += (size_t)nrec * 4;
    int*   rec_cnt  = (int*)  (ws + off); off += (size_t)nrec * 4;
    float* part_loss= (float*)(ws + off); off += (size_t)nb * 4;
    int*   part_nv  = (int*)  (ws + off);

    float* out = (float*)d_out;

    main_pass<<<nb, TPB, 0, stream>>>(scores, labels, widx,
                                      rec_week, rec_el, rec_es, rec_tl, rec_cnt,
                                      part_loss, part_nv);
    finalize<<<1, 1024, 0, stream>>>(rec_week, rec_el, rec_es, rec_tl, rec_cnt,
                                     part_loss, part_nv, nrec, nb, out);
}